// Round 1
// baseline (8396.301 us; speedup 1.0000x reference)
//
#include <hip/hip_runtime.h>
#include <hip/hip_bf16.h>

#define N_NODES 100000
#define NEDGE   600000

typedef __attribute__((ext_vector_type(8))) short bf16x8;
typedef __attribute__((ext_vector_type(4))) short s16x4;
typedef __attribute__((ext_vector_type(4))) float f32x4;

__device__ __forceinline__ short f2bf(float f) {
  union { float f; unsigned u; } x; x.f = f;
  unsigned r = x.u + 0x7FFFu + ((x.u >> 16) & 1u);
  return (short)(r >> 16);
}
__device__ __forceinline__ float bf2f(short s) {
  union { unsigned u; float f; } x; x.u = ((unsigned)(unsigned short)s) << 16; return x.f;
}

__global__ __launch_bounds__(256) void count_deg_k(const int* __restrict__ didx,
                                                   int* __restrict__ cnt) {
  int e = blockIdx.x * 256 + threadIdx.x;
  int r = blockIdx.y;
  if (e < NEDGE) atomicAdd(&cnt[r * N_NODES + didx[r * NEDGE + e]], 1);
}

__global__ __launch_bounds__(256) void make_rdeg_k(const int* __restrict__ cnt,
                                                   float* __restrict__ rdeg) {
  int i = blockIdx.x * 256 + threadIdx.x;
  if (i < 4 * N_NODES) rdeg[i] = 1.0f / (float)(cnt[i] > 1 ? cnt[i] : 1);
}

// Pack combined weights into MFMA B-fragment-linear layout:
// per (layer,type): idx = ((k0*8 + n0)*64 + lane)*8 + j
// value = W[k][n], k = k0*32 + (lane>>4)*8 + j (k<128: Wself[rA]+Wself[rB];
// 128..255: Wneigh[rA]; 256..383: Wneigh[rB]), n = n0*16 + (lane&15)
__global__ __launch_bounds__(256) void prep_w_k(const float* __restrict__ Ws1,
                                                const float* __restrict__ Wn1,
                                                const float* __restrict__ Ws2,
                                                const float* __restrict__ Wn2,
                                                short* __restrict__ WTp) {
  int tid = blockIdx.x * 256 + threadIdx.x;  // 0..98303
  int lane = tid & 63;
  int n0 = (tid >> 6) & 7;
  int idx3 = tid >> 9;       // lt*12 + k0
  int k0 = idx3 % 12;
  int lt = idx3 / 12;        // l*2 + t
  int l = lt >> 1, t = lt & 1;
  const float* Wself  = l ? Ws2 : Ws1;
  const float* Wneigh = l ? Wn2 : Wn1;
  int rA = t ? 0 : 1, rB = t ? 3 : 2;
  int n = n0 * 16 + (lane & 15);
  int kbase = k0 * 32 + (lane >> 4) * 8;
  short out[8];
#pragma unroll
  for (int j = 0; j < 8; ++j) {
    int k = kbase + j;
    int kk = k & 127, blk = k >> 7;
    float v;
    if (blk == 0)      v = Wself[rA * 16384 + kk * 128 + n] + Wself[rB * 16384 + kk * 128 + n];
    else if (blk == 1) v = Wneigh[rA * 16384 + kk * 128 + n];
    else               v = Wneigh[rB * 16384 + kk * 128 + n];
    out[j] = f2bf(v);
  }
  s16x4* dst = (s16x4*)&WTp[tid * 8];
  dst[0] = *(s16x4*)&out[0];
  dst[1] = *(s16x4*)&out[4];
}

__global__ __launch_bounds__(256) void prep_b_k(const float* __restrict__ b1,
                                                const float* __restrict__ b2,
                                                float* __restrict__ biasc) {
  int tid = blockIdx.x * 256 + threadIdx.x; // 0..511 : (l*2+t)*128 + c
  if (tid >= 512) return;
  int l = tid >> 8, t = (tid >> 7) & 1, c = tid & 127;
  const float* b = l ? b2 : b1;
  int rA = t ? 0 : 1, rB = t ? 3 : 2;
  biasc[tid] = b[rA * 128 + c] + b[rB * 128 + c];
}

template<int BF16>
__global__ __launch_bounds__(256) void scatter_k(const void* __restrict__ src,
                                                 const int* __restrict__ sidx,
                                                 const int* __restrict__ didx,
                                                 float* __restrict__ sum) {
  int tid = blockIdx.x * 256 + threadIdx.x;   // NEDGE*32 threads
  int e = tid >> 5;
  if (e >= NEDGE) return;
  int c = (tid & 31) * 4;
  int s = sidx[e], d = didx[e];
  float v0, v1, v2, v3;
  if (BF16) {
    s16x4 v = *(const s16x4*)((const short*)src + s * 128 + c);
    v0 = bf2f(v[0]); v1 = bf2f(v[1]); v2 = bf2f(v[2]); v3 = bf2f(v[3]);
  } else {
    f32x4 v = *(const f32x4*)((const float*)src + s * 128 + c);
    v0 = v[0]; v1 = v[1]; v2 = v[2]; v3 = v[3];
  }
  float* dp = sum + d * 128 + c;
  atomicAdd(dp + 0, v0);
  atomicAdd(dp + 1, v1);
  atomicAdd(dp + 2, v2);
  atomicAdd(dp + 3, v3);
}

__device__ __forceinline__ bf16x8 cvt8(const float* p, float sc) {
  f32x4 v0 = *(const f32x4*)p;
  f32x4 v1 = *(const f32x4*)(p + 4);
  bf16x8 r;
  r[0] = f2bf(v0[0] * sc); r[1] = f2bf(v0[1] * sc);
  r[2] = f2bf(v0[2] * sc); r[3] = f2bf(v0[3] * sc);
  r[4] = f2bf(v1[0] * sc); r[5] = f2bf(v1[1] * sc);
  r[6] = f2bf(v1[2] * sc); r[7] = f2bf(v1[3] * sc);
  return r;
}

// C[M=100000 x 128] = [self | sumA*rdegA | sumB*rdegB] (K=384) @ W (in LDS)
// block = 256 thr = 4 waves; wave = 32 rows (2 m-frags); block = 128 rows
template<int SELF_BF16, int OUT_RELU_BF16>
__global__ __launch_bounds__(256) void gemm_k(const void* __restrict__ selfp,
    const float* __restrict__ sumA, const float* __restrict__ sumB,
    const float* __restrict__ rdegA, const float* __restrict__ rdegB,
    const short* __restrict__ WTp, const float* __restrict__ biasc,
    void* __restrict__ outp) {
  __shared__ short Wlds[6 * 8 * 512];   // 48KB: 6 k-steps of B-fragments
  int tid = threadIdx.x;
  int lane = tid & 63, wave = tid >> 6;
  int rowbase = blockIdx.x * 128 + wave * 32;
  int r0 = rowbase + (lane & 15), r1 = r0 + 16;
  int rc0 = r0 < N_NODES ? r0 : N_NODES - 1;
  int rc1 = r1 < N_NODES ? r1 : N_NODES - 1;
  int kg = lane >> 4;
  float rdA0 = rdegA[rc0], rdA1 = rdegA[rc1];
  float rdB0 = rdegB[rc0], rdB1 = rdegB[rc1];
  f32x4 acc[2][8] = {};
  for (int half = 0; half < 2; ++half) {
    __syncthreads();
    const f32x4* s = (const f32x4*)WTp + half * 3072;
    f32x4* dst = (f32x4*)Wlds;
#pragma unroll
    for (int i = 0; i < 12; ++i) dst[tid + i * 256] = s[tid + i * 256];
    __syncthreads();
    for (int k0h = 0; k0h < 6; ++k0h) {
      int k0 = half * 6 + k0h;
      int kin = (k0 & 3) * 32 + kg * 8;
      bf16x8 a0, a1;
      if (k0 < 4) {
        if (SELF_BF16) {
          a0 = *(const bf16x8*)((const short*)selfp + rc0 * 128 + kin);
          a1 = *(const bf16x8*)((const short*)selfp + rc1 * 128 + kin);
        } else {
          const float* sp = (const float*)selfp;
          a0 = cvt8(sp + rc0 * 128 + kin, 1.0f);
          a1 = cvt8(sp + rc1 * 128 + kin, 1.0f);
        }
      } else {
        const float* sp = (k0 < 8) ? sumA : sumB;
        float s0 = (k0 < 8) ? rdA0 : rdB0;
        float s1 = (k0 < 8) ? rdA1 : rdB1;
        a0 = cvt8(sp + rc0 * 128 + kin, s0);
        a1 = cvt8(sp + rc1 * 128 + kin, s1);
      }
      const short* wb = &Wlds[k0h * 4096 + lane * 8];
#pragma unroll
      for (int n0 = 0; n0 < 8; ++n0) {
        bf16x8 b = *(const bf16x8*)(wb + n0 * 512);
        acc[0][n0] = __builtin_amdgcn_mfma_f32_16x16x32_bf16(a0, b, acc[0][n0], 0, 0, 0);
        acc[1][n0] = __builtin_amdgcn_mfma_f32_16x16x32_bf16(a1, b, acc[1][n0], 0, 0, 0);
      }
    }
  }
  // epilogue: D frag: col = n0*16 + (lane&15), row = mt*16 + (lane>>4)*4 + j
  int colb = lane & 15, rloc = kg * 4;
#pragma unroll
  for (int mt = 0; mt < 2; ++mt) {
    int rb = rowbase + mt * 16 + rloc;
#pragma unroll
    for (int n0 = 0; n0 < 8; ++n0) {
      int cc = n0 * 16 + colb;
      float bv = biasc[cc];
#pragma unroll
      for (int j = 0; j < 4; ++j) {
        int rr = rb + j;
        if (rr < N_NODES) {
          float v = acc[mt][n0][j] + bv;
          if (OUT_RELU_BF16) {
            ((short*)outp)[rr * 128 + cc] = f2bf(v > 0.f ? v : 0.f);
          } else {
            ((float*)outp)[rr * 128 + cc] = v;
          }
        }
      }
    }
  }
}

extern "C" void kernel_launch(void* const* d_in, const int* in_sizes, int n_in,
                              void* d_out, int out_size, void* d_ws, size_t ws_size,
                              hipStream_t stream) {
  (void)in_sizes; (void)n_in; (void)out_size; (void)ws_size;
  const float* xq  = (const float*)d_in[0];
  const float* xp  = (const float*)d_in[1];
  const int*   src = (const int*)d_in[2];
  const int*   dst = (const int*)d_in[3];
  const float* Ws1 = (const float*)d_in[4];
  const float* Wn1 = (const float*)d_in[5];
  const float* b1  = (const float*)d_in[6];
  const float* Ws2 = (const float*)d_in[7];
  const float* Wn2 = (const float*)d_in[8];
  const float* b2  = (const float*)d_in[9];

  char* w = (char*)d_ws;
  float* sumA  = (float*)w;  w += (size_t)N_NODES * 128 * 4;
  float* sumB  = (float*)w;  w += (size_t)N_NODES * 128 * 4;
  float* rdeg  = (float*)w;  w += (size_t)4 * N_NODES * 4;
  int*   cnt   = (int*)w;    w += (size_t)4 * N_NODES * 4;
  short* h1q   = (short*)w;  w += (size_t)N_NODES * 128 * 2;
  short* h1p   = (short*)w;  w += (size_t)N_NODES * 128 * 2;
  short* WTp   = (short*)w;  w += (size_t)4 * 49152 * 2;
  float* biasc = (float*)w;  w += 512 * 4;

  dim3 b256(256);
  const int sgrid = (NEDGE * 32) / 256;          // 75000
  const int ggrid = (N_NODES + 127) / 128;       // 782

  // degrees (dst_idx only -> once, reused by both layers)
  hipMemsetAsync(cnt, 0, (size_t)4 * N_NODES * 4, stream);
  count_deg_k<<<dim3((NEDGE + 255) / 256, 4), b256, 0, stream>>>(dst, cnt);
  make_rdeg_k<<<dim3((4 * N_NODES + 255) / 256), b256, 0, stream>>>(cnt, rdeg);
  prep_w_k<<<dim3(384), b256, 0, stream>>>(Ws1, Wn1, Ws2, Wn2, WTp);
  prep_b_k<<<dim3(2), b256, 0, stream>>>(b1, b2, biasc);

  // ---- Layer 1, type 0 (Query): rels 1,2 ; src nodes = x_product
  hipMemsetAsync(sumA, 0, (size_t)2 * N_NODES * 128 * 4, stream);
  scatter_k<0><<<sgrid, b256, 0, stream>>>(xp, src + 1 * NEDGE, dst + 1 * NEDGE, sumA);
  scatter_k<0><<<sgrid, b256, 0, stream>>>(xp, src + 2 * NEDGE, dst + 2 * NEDGE, sumB);
  gemm_k<0, 1><<<ggrid, b256, 0, stream>>>(xq, sumA, sumB,
      rdeg + 1 * N_NODES, rdeg + 2 * N_NODES, WTp + 0 * 49152, biasc + 0, h1q);

  // ---- Layer 1, type 1 (Product): rels 0,3 ; src = x_query
  hipMemsetAsync(sumA, 0, (size_t)2 * N_NODES * 128 * 4, stream);
  scatter_k<0><<<sgrid, b256, 0, stream>>>(xq, src + 0 * NEDGE, dst + 0 * NEDGE, sumA);
  scatter_k<0><<<sgrid, b256, 0, stream>>>(xq, src + 3 * NEDGE, dst + 3 * NEDGE, sumB);
  gemm_k<0, 1><<<ggrid, b256, 0, stream>>>(xp, sumA, sumB,
      rdeg + 0 * N_NODES, rdeg + 3 * N_NODES, WTp + 1 * 49152, biasc + 128, h1p);

  // ---- Layer 2, type 0 (Query): rels 1,2 ; src = h1p (bf16)
  hipMemsetAsync(sumA, 0, (size_t)2 * N_NODES * 128 * 4, stream);
  scatter_k<1><<<sgrid, b256, 0, stream>>>(h1p, src + 1 * NEDGE, dst + 1 * NEDGE, sumA);
  scatter_k<1><<<sgrid, b256, 0, stream>>>(h1p, src + 2 * NEDGE, dst + 2 * NEDGE, sumB);
  gemm_k<1, 0><<<ggrid, b256, 0, stream>>>(h1q, sumA, sumB,
      rdeg + 1 * N_NODES, rdeg + 2 * N_NODES, WTp + 2 * 49152, biasc + 256, (float*)d_out);

  // ---- Layer 2, type 1 (Product): rels 0,3 ; src = h1q (bf16)
  hipMemsetAsync(sumA, 0, (size_t)2 * N_NODES * 128 * 4, stream);
  scatter_k<1><<<sgrid, b256, 0, stream>>>(h1q, src + 0 * NEDGE, dst + 0 * NEDGE, sumA);
  scatter_k<1><<<sgrid, b256, 0, stream>>>(h1q, src + 3 * NEDGE, dst + 3 * NEDGE, sumB);
  gemm_k<1, 0><<<ggrid, b256, 0, stream>>>(h1p, sumA, sumB,
      rdeg + 0 * N_NODES, rdeg + 3 * N_NODES, WTp + 3 * 49152, biasc + 384,
      (float*)d_out + (size_t)N_NODES * 128);
}

// Round 2
// 1084.528 us; speedup vs baseline: 7.7419x; 7.7419x over previous
//
#include <hip/hip_runtime.h>
#include <hip/hip_bf16.h>

#define N_NODES 100000
#define NEDGE   600000

typedef __attribute__((ext_vector_type(8))) short bf16x8;
typedef __attribute__((ext_vector_type(4))) short s16x4;
typedef __attribute__((ext_vector_type(4))) float f32x4;

__device__ __forceinline__ short f2bf(float f) {
  union { float f; unsigned u; } x; x.f = f;
  unsigned r = x.u + 0x7FFFu + ((x.u >> 16) & 1u);
  return (short)(r >> 16);
}

__global__ __launch_bounds__(256) void count_deg_k(const int* __restrict__ didx,
                                                   int* __restrict__ cnt) {
  int e = blockIdx.x * 256 + threadIdx.x;
  int r = blockIdx.y;
  if (e < NEDGE) atomicAdd(&cnt[r * N_NODES + didx[r * NEDGE + e]], 1);
}

// one block per relation: exclusive scan of cnt[r][0..N) -> off[r][0..N]
__global__ __launch_bounds__(1024) void scan_k(const int* __restrict__ cnt,
                                               int* __restrict__ off) {
  __shared__ int buf[1024];
  int r = blockIdx.x, t = threadIdx.x;
  const int per = (N_NODES + 1023) / 1024;
  int base = t * per;
  int s = 0;
  for (int j = 0; j < per; ++j) {
    int i = base + j;
    if (i < N_NODES) s += cnt[r * N_NODES + i];
  }
  buf[t] = s;
  __syncthreads();
  for (int st = 1; st < 1024; st <<= 1) {
    int x = (t >= st) ? buf[t - st] : 0;
    __syncthreads();
    buf[t] += x;
    __syncthreads();
  }
  int run = buf[t] - s;   // exclusive prefix
  for (int j = 0; j < per; ++j) {
    int i = base + j;
    if (i < N_NODES) {
      off[r * (N_NODES + 1) + i] = run;
      run += cnt[r * N_NODES + i];
    }
  }
  if (t == 1023) off[r * (N_NODES + 1) + N_NODES] = buf[1023];
}

__global__ __launch_bounds__(256) void fill_csr_k(const int* __restrict__ sidx,
                                                  const int* __restrict__ didx,
                                                  const int* __restrict__ off,
                                                  int* __restrict__ cursor,
                                                  int* __restrict__ csr) {
  int e = blockIdx.x * 256 + threadIdx.x;
  int r = blockIdx.y;
  if (e >= NEDGE) return;
  int d = didx[r * NEDGE + e];
  int pos = off[r * (N_NODES + 1) + d] + atomicAdd(&cursor[r * N_NODES + d], 1);
  csr[r * NEDGE + pos] = sidx[r * NEDGE + e];
}

// Pack combined weights into MFMA B-fragment-linear layout (see round 1).
__global__ __launch_bounds__(256) void prep_w_k(const float* __restrict__ Ws1,
                                                const float* __restrict__ Wn1,
                                                const float* __restrict__ Ws2,
                                                const float* __restrict__ Wn2,
                                                short* __restrict__ WTp) {
  int tid = blockIdx.x * 256 + threadIdx.x;  // 0..98303
  int lane = tid & 63;
  int n0 = (tid >> 6) & 7;
  int idx3 = tid >> 9;
  int k0 = idx3 % 12;
  int lt = idx3 / 12;
  int l = lt >> 1, t = lt & 1;
  const float* Wself  = l ? Ws2 : Ws1;
  const float* Wneigh = l ? Wn2 : Wn1;
  int rA = t ? 0 : 1, rB = t ? 3 : 2;
  int n = n0 * 16 + (lane & 15);
  int kbase = k0 * 32 + (lane >> 4) * 8;
  short out[8];
#pragma unroll
  for (int j = 0; j < 8; ++j) {
    int k = kbase + j;
    int kk = k & 127, blk = k >> 7;
    float v;
    if (blk == 0)      v = Wself[rA * 16384 + kk * 128 + n] + Wself[rB * 16384 + kk * 128 + n];
    else if (blk == 1) v = Wneigh[rA * 16384 + kk * 128 + n];
    else               v = Wneigh[rB * 16384 + kk * 128 + n];
    out[j] = f2bf(v);
  }
  s16x4* dst = (s16x4*)&WTp[tid * 8];
  dst[0] = *(s16x4*)&out[0];
  dst[1] = *(s16x4*)&out[4];
}

__global__ __launch_bounds__(256) void prep_b_k(const float* __restrict__ b1,
                                                const float* __restrict__ b2,
                                                float* __restrict__ biasc) {
  int tid = blockIdx.x * 256 + threadIdx.x;
  if (tid >= 512) return;
  int l = tid >> 8, t = (tid >> 7) & 1, c = tid & 127;
  const float* b = l ? b2 : b1;
  int rA = t ? 0 : 1, rB = t ? 3 : 2;
  biasc[tid] = b[rA * 128 + c] + b[rB * 128 + c];
}

// One wave per dst node; gathers rows for relations A and B, writes bf16 means.
// lane handles cols {2*lane, 2*lane+1}.
template<int SRC_BF16>
__global__ __launch_bounds__(256) void gather_mean_k(const void* __restrict__ src,
    const int* __restrict__ csrA, const int* __restrict__ offA,
    const int* __restrict__ csrB, const int* __restrict__ offB,
    unsigned* __restrict__ meanA, unsigned* __restrict__ meanB) {
  int gid = blockIdx.x * 256 + threadIdx.x;
  int n = gid >> 6;
  int lane = gid & 63;
  if (n >= N_NODES) return;
#pragma unroll
  for (int rel = 0; rel < 2; ++rel) {
    const int* csr = rel ? csrB : csrA;
    const int* off = rel ? offB : offA;
    unsigned* mean = rel ? meanB : meanA;
    int p0 = off[n], p1 = off[n + 1];
    float a0 = 0.f, a1 = 0.f;
    for (int p = p0; p < p1; ++p) {
      int sidx = csr[p];
      if (SRC_BF16) {
        unsigned u = *((const unsigned*)src + (size_t)sidx * 64 + lane);
        union { unsigned u; float f; } x0, x1;
        x0.u = u << 16; x1.u = u & 0xffff0000u;
        a0 += x0.f; a1 += x1.f;
      } else {
        const float* fp = (const float*)src + (size_t)sidx * 128 + lane * 2;
        a0 += fp[0]; a1 += fp[1];
      }
    }
    int deg = p1 - p0;
    float inv = 1.0f / (float)(deg > 1 ? deg : 1);
    unsigned w = (unsigned)(unsigned short)f2bf(a0 * inv) |
                 ((unsigned)(unsigned short)f2bf(a1 * inv) << 16);
    mean[(size_t)n * 64 + lane] = w;
  }
}

// C[M=100000 x 128] = [self | meanA | meanB] (K=384, all bf16 except f32 self L1) @ W
// block = 256 thr = 4 waves; wave = 32 rows (2 m-frags); block = 128 rows
template<int SELF_BF16, int OUT_RELU_BF16>
__global__ __launch_bounds__(256) void gemm_k(const void* __restrict__ selfp,
    const short* __restrict__ meanA, const short* __restrict__ meanB,
    const short* __restrict__ WTp, const float* __restrict__ biasc,
    void* __restrict__ outp) {
  __shared__ short Wlds[6 * 8 * 512];   // 48KB: 6 k-steps of B-fragments
  int tid = threadIdx.x;
  int lane = tid & 63, wave = tid >> 6;
  int rowbase = blockIdx.x * 128 + wave * 32;
  int r0 = rowbase + (lane & 15), r1 = r0 + 16;
  int rc0 = r0 < N_NODES ? r0 : N_NODES - 1;
  int rc1 = r1 < N_NODES ? r1 : N_NODES - 1;
  int kg = lane >> 4;
  f32x4 acc[2][8] = {};
  for (int half = 0; half < 2; ++half) {
    __syncthreads();
    const f32x4* s = (const f32x4*)WTp + half * 3072;
    f32x4* dst = (f32x4*)Wlds;
#pragma unroll
    for (int i = 0; i < 12; ++i) dst[tid + i * 256] = s[tid + i * 256];
    __syncthreads();
    for (int k0h = 0; k0h < 6; ++k0h) {
      int k0 = half * 6 + k0h;
      int kin = (k0 & 3) * 32 + kg * 8;
      bf16x8 a0, a1;
      if (k0 < 4) {
        if (SELF_BF16) {
          a0 = *(const bf16x8*)((const short*)selfp + (size_t)rc0 * 128 + kin);
          a1 = *(const bf16x8*)((const short*)selfp + (size_t)rc1 * 128 + kin);
        } else {
          const float* sp = (const float*)selfp;
          const f32x4* q00 = (const f32x4*)(sp + (size_t)rc0 * 128 + kin);
          const f32x4* q10 = (const f32x4*)(sp + (size_t)rc1 * 128 + kin);
          f32x4 v00 = q00[0], v01 = q00[1], v10 = q10[0], v11 = q10[1];
#pragma unroll
          for (int j = 0; j < 4; ++j) {
            a0[j] = f2bf(v00[j]); a0[j + 4] = f2bf(v01[j]);
            a1[j] = f2bf(v10[j]); a1[j + 4] = f2bf(v11[j]);
          }
        }
      } else {
        const short* mp = (k0 < 8) ? meanA : meanB;
        a0 = *(const bf16x8*)(mp + (size_t)rc0 * 128 + kin);
        a1 = *(const bf16x8*)(mp + (size_t)rc1 * 128 + kin);
      }
      const short* wb = &Wlds[k0h * 4096 + lane * 8];
#pragma unroll
      for (int n0 = 0; n0 < 8; ++n0) {
        bf16x8 b = *(const bf16x8*)(wb + n0 * 512);
        acc[0][n0] = __builtin_amdgcn_mfma_f32_16x16x32_bf16(a0, b, acc[0][n0], 0, 0, 0);
        acc[1][n0] = __builtin_amdgcn_mfma_f32_16x16x32_bf16(a1, b, acc[1][n0], 0, 0, 0);
      }
    }
  }
  int colb = lane & 15, rloc = kg * 4;
#pragma unroll
  for (int mt = 0; mt < 2; ++mt) {
    int rb = rowbase + mt * 16 + rloc;
#pragma unroll
    for (int n0 = 0; n0 < 8; ++n0) {
      int cc = n0 * 16 + colb;
      float bv = biasc[cc];
#pragma unroll
      for (int j = 0; j < 4; ++j) {
        int rr = rb + j;
        if (rr < N_NODES) {
          float v = acc[mt][n0][j] + bv;
          if (OUT_RELU_BF16) {
            ((short*)outp)[(size_t)rr * 128 + cc] = f2bf(v > 0.f ? v : 0.f);
          } else {
            ((float*)outp)[(size_t)rr * 128 + cc] = v;
          }
        }
      }
    }
  }
}

extern "C" void kernel_launch(void* const* d_in, const int* in_sizes, int n_in,
                              void* d_out, int out_size, void* d_ws, size_t ws_size,
                              hipStream_t stream) {
  (void)in_sizes; (void)n_in; (void)out_size; (void)ws_size;
  const float* xq  = (const float*)d_in[0];
  const float* xp  = (const float*)d_in[1];
  const int*   src = (const int*)d_in[2];
  const int*   dst = (const int*)d_in[3];
  const float* Ws1 = (const float*)d_in[4];
  const float* Wn1 = (const float*)d_in[5];
  const float* b1  = (const float*)d_in[6];
  const float* Ws2 = (const float*)d_in[7];
  const float* Wn2 = (const float*)d_in[8];
  const float* b2  = (const float*)d_in[9];

  char* w = (char*)d_ws;
  int*   cnt    = (int*)w;      w += (size_t)4 * N_NODES * 4;
  int*   cursor = (int*)w;      w += (size_t)4 * N_NODES * 4;
  int*   off    = (int*)w;      w += (size_t)4 * (N_NODES + 1) * 4;
  int*   csr    = (int*)w;      w += (size_t)4 * NEDGE * 4;
  short* meanA  = (short*)w;    w += (size_t)N_NODES * 128 * 2;
  short* meanB  = (short*)w;    w += (size_t)N_NODES * 128 * 2;
  short* h1q    = (short*)w;    w += (size_t)N_NODES * 128 * 2;
  short* h1p    = (short*)w;    w += (size_t)N_NODES * 128 * 2;
  short* WTp    = (short*)w;    w += (size_t)4 * 49152 * 2;
  float* biasc  = (float*)w;    w += 512 * 4;

  dim3 b256(256);
  const int egrid = (NEDGE + 255) / 256;         // 2344
  const int ggrid = (N_NODES + 127) / 128;       // 782
  const int ngrid = (N_NODES + 3) / 4;           // 25000 (4 waves/block)

  const int NP1 = N_NODES + 1;

  // --- CSR build (dst_idx fixed -> once per call, reused by both layers)
  hipMemsetAsync(cnt, 0, (size_t)8 * N_NODES * 4, stream);   // cnt + cursor
  count_deg_k<<<dim3(egrid, 4), b256, 0, stream>>>(dst, cnt);
  scan_k<<<dim3(4), dim3(1024), 0, stream>>>(cnt, off);
  fill_csr_k<<<dim3(egrid, 4), b256, 0, stream>>>(src, dst, off, cursor, csr);
  prep_w_k<<<dim3(384), b256, 0, stream>>>(Ws1, Wn1, Ws2, Wn2, WTp);
  prep_b_k<<<dim3(2), b256, 0, stream>>>(b1, b2, biasc);

  // ---- Layer 1, type 0 (Query): rels 1,2 ; src nodes = x_product (f32)
  gather_mean_k<0><<<ngrid, b256, 0, stream>>>(xp,
      csr + 1 * NEDGE, off + 1 * NP1, csr + 2 * NEDGE, off + 2 * NP1,
      (unsigned*)meanA, (unsigned*)meanB);
  gemm_k<0, 1><<<ggrid, b256, 0, stream>>>(xq, meanA, meanB,
      WTp + 0 * 49152, biasc + 0, h1q);

  // ---- Layer 1, type 1 (Product): rels 0,3 ; src = x_query (f32)
  gather_mean_k<0><<<ngrid, b256, 0, stream>>>(xq,
      csr + 0 * NEDGE, off + 0 * NP1, csr + 3 * NEDGE, off + 3 * NP1,
      (unsigned*)meanA, (unsigned*)meanB);
  gemm_k<0, 1><<<ggrid, b256, 0, stream>>>(xp, meanA, meanB,
      WTp + 1 * 49152, biasc + 128, h1p);

  // ---- Layer 2, type 0 (Query): rels 1,2 ; src = h1p (bf16)
  gather_mean_k<1><<<ngrid, b256, 0, stream>>>(h1p,
      csr + 1 * NEDGE, off + 1 * NP1, csr + 2 * NEDGE, off + 2 * NP1,
      (unsigned*)meanA, (unsigned*)meanB);
  gemm_k<1, 0><<<ggrid, b256, 0, stream>>>(h1q, meanA, meanB,
      WTp + 2 * 49152, biasc + 256, (float*)d_out);

  // ---- Layer 2, type 1 (Product): rels 0,3 ; src = h1q (bf16)
  gather_mean_k<1><<<ngrid, b256, 0, stream>>>(h1q,
      csr + 0 * NEDGE, off + 0 * NP1, csr + 3 * NEDGE, off + 3 * NP1,
      (unsigned*)meanA, (unsigned*)meanB);
  gemm_k<1, 0><<<ggrid, b256, 0, stream>>>(h1p, meanA, meanB,
      WTp + 3 * 49152, biasc + 384, (float*)d_out + (size_t)N_NODES * 128);
}

// Round 3
// 901.304 us; speedup vs baseline: 9.3157x; 1.2033x over previous
//
#include <hip/hip_runtime.h>
#include <hip/hip_bf16.h>

#define N_NODES 100000
#define NEDGE   600000
#define SCAN_B  1024
#define NBLK    98            // ceil(N_NODES / SCAN_B)

typedef __attribute__((ext_vector_type(8))) short bf16x8;
typedef __attribute__((ext_vector_type(4))) short s16x4;
typedef __attribute__((ext_vector_type(4))) float f32x4;

__device__ __forceinline__ short f2bf(float f) {
  union { float f; unsigned u; } x; x.f = f;
  unsigned r = x.u + 0x7FFFu + ((x.u >> 16) & 1u);
  return (short)(r >> 16);
}

__global__ __launch_bounds__(256) void count_deg_k(const int* __restrict__ didx,
                                                   int* __restrict__ cnt) {
  int e = blockIdx.x * 256 + threadIdx.x;
  int r = blockIdx.y;
  if (e < NEDGE) atomicAdd(&cnt[r * N_NODES + didx[r * NEDGE + e]], 1);
}

// Phase 1: per-block chunk sums. grid (NBLK, 4), 256 thr, 4 elems/thr.
__global__ __launch_bounds__(256) void scan1_k(const int* __restrict__ cnt,
                                               int* __restrict__ bsum) {
  __shared__ int lds[256];
  int b = blockIdx.x, r = blockIdx.y, t = threadIdx.x;
  int i0 = b * SCAN_B + t * 4;
  int s = 0;
#pragma unroll
  for (int j = 0; j < 4; ++j)
    if (i0 + j < N_NODES) s += cnt[r * N_NODES + i0 + j];
  lds[t] = s;
  __syncthreads();
  for (int st = 128; st > 0; st >>= 1) {
    if (t < st) lds[t] += lds[t + st];
    __syncthreads();
  }
  if (t == 0) bsum[r * NBLK + b] = lds[0];
}

// Phase 2: exclusive scan of the NBLK block sums per relation. 1 block, 128 thr.
__global__ __launch_bounds__(128) void scan2_k(int* __restrict__ bsum) {
  __shared__ int buf[128];
  int t = threadIdx.x;
  for (int r = 0; r < 4; ++r) {
    int v = (t < NBLK) ? bsum[r * NBLK + t] : 0;
    buf[t] = v;
    __syncthreads();
    for (int st = 1; st < 128; st <<= 1) {
      int x = (t >= st) ? buf[t - st] : 0;
      __syncthreads();
      buf[t] += x;
      __syncthreads();
    }
    if (t < NBLK) bsum[r * NBLK + t] = buf[t] - v;   // exclusive
    __syncthreads();
  }
}

// Phase 3: local exclusive scan + block base -> off. grid (NBLK, 4), 256 thr.
__global__ __launch_bounds__(256) void scan3_k(const int* __restrict__ cnt,
                                               const int* __restrict__ bsum,
                                               int* __restrict__ off) {
  __shared__ int lds[256];
  int b = blockIdx.x, r = blockIdx.y, t = threadIdx.x;
  int i0 = b * SCAN_B + t * 4;
  int c[4] = {0, 0, 0, 0};
#pragma unroll
  for (int j = 0; j < 4; ++j)
    if (i0 + j < N_NODES) c[j] = cnt[r * N_NODES + i0 + j];
  int s = c[0] + c[1] + c[2] + c[3];
  lds[t] = s;
  __syncthreads();
  for (int st = 1; st < 256; st <<= 1) {
    int x = (t >= st) ? lds[t - st] : 0;
    __syncthreads();
    lds[t] += x;
    __syncthreads();
  }
  int run = bsum[r * NBLK + b] + lds[t] - s;   // exclusive prefix for this thread
  int* o = off + r * (N_NODES + 1);
#pragma unroll
  for (int j = 0; j < 4; ++j) {
    if (i0 + j < N_NODES) { o[i0 + j] = run; run += c[j]; }
  }
  if (b == 0 && t == 0) o[N_NODES] = NEDGE;
}

__global__ __launch_bounds__(256) void fill_csr_k(const int* __restrict__ sidx,
                                                  const int* __restrict__ didx,
                                                  const int* __restrict__ off,
                                                  int* __restrict__ cursor,
                                                  int* __restrict__ csr) {
  int e = blockIdx.x * 256 + threadIdx.x;
  int r = blockIdx.y;
  if (e >= NEDGE) return;
  int d = didx[r * NEDGE + e];
  int pos = off[r * (N_NODES + 1) + d] + atomicAdd(&cursor[r * N_NODES + d], 1);
  csr[r * NEDGE + pos] = sidx[r * NEDGE + e];
}

// Pack combined weights into MFMA B-fragment-linear layout.
__global__ __launch_bounds__(256) void prep_w_k(const float* __restrict__ Ws1,
                                                const float* __restrict__ Wn1,
                                                const float* __restrict__ Ws2,
                                                const float* __restrict__ Wn2,
                                                short* __restrict__ WTp) {
  int tid = blockIdx.x * 256 + threadIdx.x;  // 0..98303
  int lane = tid & 63;
  int n0 = (tid >> 6) & 7;
  int idx3 = tid >> 9;
  int k0 = idx3 % 12;
  int lt = idx3 / 12;
  int l = lt >> 1, t = lt & 1;
  const float* Wself  = l ? Ws2 : Ws1;
  const float* Wneigh = l ? Wn2 : Wn1;
  int rA = t ? 0 : 1, rB = t ? 3 : 2;
  int n = n0 * 16 + (lane & 15);
  int kbase = k0 * 32 + (lane >> 4) * 8;
  short out[8];
#pragma unroll
  for (int j = 0; j < 8; ++j) {
    int k = kbase + j;
    int kk = k & 127, blk = k >> 7;
    float v;
    if (blk == 0)      v = Wself[rA * 16384 + kk * 128 + n] + Wself[rB * 16384 + kk * 128 + n];
    else if (blk == 1) v = Wneigh[rA * 16384 + kk * 128 + n];
    else               v = Wneigh[rB * 16384 + kk * 128 + n];
    out[j] = f2bf(v);
  }
  s16x4* dst = (s16x4*)&WTp[tid * 8];
  dst[0] = *(s16x4*)&out[0];
  dst[1] = *(s16x4*)&out[4];
}

__global__ __launch_bounds__(256) void prep_b_k(const float* __restrict__ b1,
                                                const float* __restrict__ b2,
                                                float* __restrict__ biasc) {
  int tid = blockIdx.x * 256 + threadIdx.x;
  if (tid >= 512) return;
  int l = tid >> 8, t = (tid >> 7) & 1, c = tid & 127;
  const float* b = l ? b2 : b1;
  int rA = t ? 0 : 1, rB = t ? 3 : 2;
  biasc[tid] = b[rA * 128 + c] + b[rB * 128 + c];
}

// One wave per dst node; gathers rows for relations A and B, writes bf16 means.
template<int SRC_BF16>
__global__ __launch_bounds__(256) void gather_mean_k(const void* __restrict__ src,
    const int* __restrict__ csrA, const int* __restrict__ offA,
    const int* __restrict__ csrB, const int* __restrict__ offB,
    unsigned* __restrict__ meanA, unsigned* __restrict__ meanB) {
  int gid = blockIdx.x * 256 + threadIdx.x;
  int n = gid >> 6;
  int lane = gid & 63;
  if (n >= N_NODES) return;
#pragma unroll
  for (int rel = 0; rel < 2; ++rel) {
    const int* csr = rel ? csrB : csrA;
    const int* off = rel ? offB : offA;
    unsigned* mean = rel ? meanB : meanA;
    int p0 = off[n], p1 = off[n + 1];
    float a0 = 0.f, a1 = 0.f;
    for (int p = p0; p < p1; ++p) {
      int sidx = csr[p];
      if (SRC_BF16) {
        unsigned u = *((const unsigned*)src + (size_t)sidx * 64 + lane);
        union { unsigned u; float f; } x0, x1;
        x0.u = u << 16; x1.u = u & 0xffff0000u;
        a0 += x0.f; a1 += x1.f;
      } else {
        const float* fp = (const float*)src + (size_t)sidx * 128 + lane * 2;
        a0 += fp[0]; a1 += fp[1];
      }
    }
    int deg = p1 - p0;
    float inv = 1.0f / (float)(deg > 1 ? deg : 1);
    unsigned w = (unsigned)(unsigned short)f2bf(a0 * inv) |
                 ((unsigned)(unsigned short)f2bf(a1 * inv) << 16);
    mean[(size_t)n * 64 + lane] = w;
  }
}

// C[M=100000 x 128] = [self | meanA | meanB] (K=384) @ W (in LDS)
template<int SELF_BF16, int OUT_RELU_BF16>
__global__ __launch_bounds__(256) void gemm_k(const void* __restrict__ selfp,
    const short* __restrict__ meanA, const short* __restrict__ meanB,
    const short* __restrict__ WTp, const float* __restrict__ biasc,
    void* __restrict__ outp) {
  __shared__ short Wlds[6 * 8 * 512];   // 48KB
  int tid = threadIdx.x;
  int lane = tid & 63, wave = tid >> 6;
  int rowbase = blockIdx.x * 128 + wave * 32;
  int r0 = rowbase + (lane & 15), r1 = r0 + 16;
  int rc0 = r0 < N_NODES ? r0 : N_NODES - 1;
  int rc1 = r1 < N_NODES ? r1 : N_NODES - 1;
  int kg = lane >> 4;
  f32x4 acc[2][8] = {};
  for (int half = 0; half < 2; ++half) {
    __syncthreads();
    const f32x4* s = (const f32x4*)WTp + half * 3072;
    f32x4* dst = (f32x4*)Wlds;
#pragma unroll
    for (int i = 0; i < 12; ++i) dst[tid + i * 256] = s[tid + i * 256];
    __syncthreads();
    for (int k0h = 0; k0h < 6; ++k0h) {
      int k0 = half * 6 + k0h;
      int kin = (k0 & 3) * 32 + kg * 8;
      bf16x8 a0, a1;
      if (k0 < 4) {
        if (SELF_BF16) {
          a0 = *(const bf16x8*)((const short*)selfp + (size_t)rc0 * 128 + kin);
          a1 = *(const bf16x8*)((const short*)selfp + (size_t)rc1 * 128 + kin);
        } else {
          const float* sp = (const float*)selfp;
          const f32x4* q00 = (const f32x4*)(sp + (size_t)rc0 * 128 + kin);
          const f32x4* q10 = (const f32x4*)(sp + (size_t)rc1 * 128 + kin);
          f32x4 v00 = q00[0], v01 = q00[1], v10 = q10[0], v11 = q10[1];
#pragma unroll
          for (int j = 0; j < 4; ++j) {
            a0[j] = f2bf(v00[j]); a0[j + 4] = f2bf(v01[j]);
            a1[j] = f2bf(v10[j]); a1[j + 4] = f2bf(v11[j]);
          }
        }
      } else {
        const short* mp = (k0 < 8) ? meanA : meanB;
        a0 = *(const bf16x8*)(mp + (size_t)rc0 * 128 + kin);
        a1 = *(const bf16x8*)(mp + (size_t)rc1 * 128 + kin);
      }
      const short* wb = &Wlds[k0h * 4096 + lane * 8];
#pragma unroll
      for (int n0 = 0; n0 < 8; ++n0) {
        bf16x8 b = *(const bf16x8*)(wb + n0 * 512);
        acc[0][n0] = __builtin_amdgcn_mfma_f32_16x16x32_bf16(a0, b, acc[0][n0], 0, 0, 0);
        acc[1][n0] = __builtin_amdgcn_mfma_f32_16x16x32_bf16(a1, b, acc[1][n0], 0, 0, 0);
      }
    }
  }
  int colb = lane & 15, rloc = kg * 4;
#pragma unroll
  for (int mt = 0; mt < 2; ++mt) {
    int rb = rowbase + mt * 16 + rloc;
#pragma unroll
    for (int n0 = 0; n0 < 8; ++n0) {
      int cc = n0 * 16 + colb;
      float bv = biasc[cc];
#pragma unroll
      for (int j = 0; j < 4; ++j) {
        int rr = rb + j;
        if (rr < N_NODES) {
          float v = acc[mt][n0][j] + bv;
          if (OUT_RELU_BF16) {
            ((short*)outp)[(size_t)rr * 128 + cc] = f2bf(v > 0.f ? v : 0.f);
          } else {
            ((float*)outp)[(size_t)rr * 128 + cc] = v;
          }
        }
      }
    }
  }
}

extern "C" void kernel_launch(void* const* d_in, const int* in_sizes, int n_in,
                              void* d_out, int out_size, void* d_ws, size_t ws_size,
                              hipStream_t stream) {
  (void)in_sizes; (void)n_in; (void)out_size; (void)ws_size;
  const float* xq  = (const float*)d_in[0];
  const float* xp  = (const float*)d_in[1];
  const int*   src = (const int*)d_in[2];
  const int*   dst = (const int*)d_in[3];
  const float* Ws1 = (const float*)d_in[4];
  const float* Wn1 = (const float*)d_in[5];
  const float* b1  = (const float*)d_in[6];
  const float* Ws2 = (const float*)d_in[7];
  const float* Wn2 = (const float*)d_in[8];
  const float* b2  = (const float*)d_in[9];

  char* w = (char*)d_ws;
  int*   cnt    = (int*)w;      w += (size_t)4 * N_NODES * 4;
  int*   cursor = (int*)w;      w += (size_t)4 * N_NODES * 4;
  int*   off    = (int*)w;      w += (size_t)4 * (N_NODES + 1) * 4;
  int*   csr    = (int*)w;      w += (size_t)4 * NEDGE * 4;
  short* meanA  = (short*)w;    w += (size_t)N_NODES * 128 * 2;
  short* meanB  = (short*)w;    w += (size_t)N_NODES * 128 * 2;
  short* h1q    = (short*)w;    w += (size_t)N_NODES * 128 * 2;
  short* h1p    = (short*)w;    w += (size_t)N_NODES * 128 * 2;
  short* WTp    = (short*)w;    w += (size_t)4 * 49152 * 2;
  float* biasc  = (float*)w;    w += 512 * 4;
  int*   bsum   = (int*)w;      w += 4 * 128 * 4;

  dim3 b256(256);
  const int egrid = (NEDGE + 255) / 256;         // 2344
  const int ggrid = (N_NODES + 127) / 128;       // 782
  const int ngrid = (N_NODES + 3) / 4;           // 25000 (4 waves/block)
  const int NP1 = N_NODES + 1;

  // --- CSR build (dst_idx fixed -> once per call, reused by both layers)
  hipMemsetAsync(cnt, 0, (size_t)8 * N_NODES * 4, stream);   // cnt + cursor
  count_deg_k<<<dim3(egrid, 4), b256, 0, stream>>>(dst, cnt);
  scan1_k<<<dim3(NBLK, 4), b256, 0, stream>>>(cnt, bsum);
  scan2_k<<<dim3(1), dim3(128), 0, stream>>>(bsum);
  scan3_k<<<dim3(NBLK, 4), b256, 0, stream>>>(cnt, bsum, off);
  fill_csr_k<<<dim3(egrid, 4), b256, 0, stream>>>(src, dst, off, cursor, csr);
  prep_w_k<<<dim3(384), b256, 0, stream>>>(Ws1, Wn1, Ws2, Wn2, WTp);
  prep_b_k<<<dim3(2), b256, 0, stream>>>(b1, b2, biasc);

  // ---- Layer 1, type 0 (Query): rels 1,2 ; src nodes = x_product (f32)
  gather_mean_k<0><<<ngrid, b256, 0, stream>>>(xp,
      csr + 1 * NEDGE, off + 1 * NP1, csr + 2 * NEDGE, off + 2 * NP1,
      (unsigned*)meanA, (unsigned*)meanB);
  gemm_k<0, 1><<<ggrid, b256, 0, stream>>>(xq, meanA, meanB,
      WTp + 0 * 49152, biasc + 0, h1q);

  // ---- Layer 1, type 1 (Product): rels 0,3 ; src = x_query (f32)
  gather_mean_k<0><<<ngrid, b256, 0, stream>>>(xq,
      csr + 0 * NEDGE, off + 0 * NP1, csr + 3 * NEDGE, off + 3 * NP1,
      (unsigned*)meanA, (unsigned*)meanB);
  gemm_k<0, 1><<<ggrid, b256, 0, stream>>>(xp, meanA, meanB,
      WTp + 1 * 49152, biasc + 128, h1p);

  // ---- Layer 2, type 0 (Query): rels 1,2 ; src = h1p (bf16)
  gather_mean_k<1><<<ngrid, b256, 0, stream>>>(h1p,
      csr + 1 * NEDGE, off + 1 * NP1, csr + 2 * NEDGE, off + 2 * NP1,
      (unsigned*)meanA, (unsigned*)meanB);
  gemm_k<1, 0><<<ggrid, b256, 0, stream>>>(h1q, meanA, meanB,
      WTp + 2 * 49152, biasc + 256, (float*)d_out);

  // ---- Layer 2, type 1 (Product): rels 0,3 ; src = h1q (bf16)
  gather_mean_k<1><<<ngrid, b256, 0, stream>>>(h1q,
      csr + 0 * NEDGE, off + 0 * NP1, csr + 3 * NEDGE, off + 3 * NP1,
      (unsigned*)meanA, (unsigned*)meanB);
  gemm_k<1, 0><<<ggrid, b256, 0, stream>>>(h1p, meanA, meanB,
      WTp + 3 * 49152, biasc + 384, (float*)d_out + (size_t)N_NODES * 128);
}

// Round 4
// 720.081 us; speedup vs baseline: 11.6602x; 1.2517x over previous
//
#include <hip/hip_runtime.h>
#include <hip/hip_bf16.h>

#define N_NODES 100000
#define NEDGE   600000
#define SCAN_B  1024
#define NBLK    98            // ceil(N_NODES / SCAN_B)

typedef __attribute__((ext_vector_type(8))) short bf16x8;
typedef __attribute__((ext_vector_type(4))) short s16x4;
typedef __attribute__((ext_vector_type(4))) float f32x4;

__device__ __forceinline__ short f2bf(float f) {
  union { float f; unsigned u; } x; x.f = f;
  unsigned r = x.u + 0x7FFFu + ((x.u >> 16) & 1u);
  return (short)(r >> 16);
}

__global__ __launch_bounds__(256) void count_deg_k(const int* __restrict__ didx,
                                                   int* __restrict__ cnt) {
  int e = blockIdx.x * 256 + threadIdx.x;
  int r = blockIdx.y;
  if (e < NEDGE) atomicAdd(&cnt[r * N_NODES + didx[r * NEDGE + e]], 1);
}

// Phase 1: per-block chunk sums. grid (NBLK, 4), 256 thr, 4 elems/thr.
__global__ __launch_bounds__(256) void scan1_k(const int* __restrict__ cnt,
                                               int* __restrict__ bsum) {
  __shared__ int lds[256];
  int b = blockIdx.x, r = blockIdx.y, t = threadIdx.x;
  int i0 = b * SCAN_B + t * 4;
  int s = 0;
#pragma unroll
  for (int j = 0; j < 4; ++j)
    if (i0 + j < N_NODES) s += cnt[r * N_NODES + i0 + j];
  lds[t] = s;
  __syncthreads();
  for (int st = 128; st > 0; st >>= 1) {
    if (t < st) lds[t] += lds[t + st];
    __syncthreads();
  }
  if (t == 0) bsum[r * NBLK + b] = lds[0];
}

// Phase 2: exclusive scan of the NBLK block sums per relation. 1 block, 128 thr.
__global__ __launch_bounds__(128) void scan2_k(int* __restrict__ bsum) {
  __shared__ int buf[128];
  int t = threadIdx.x;
  for (int r = 0; r < 4; ++r) {
    int v = (t < NBLK) ? bsum[r * NBLK + t] : 0;
    buf[t] = v;
    __syncthreads();
    for (int st = 1; st < 128; st <<= 1) {
      int x = (t >= st) ? buf[t - st] : 0;
      __syncthreads();
      buf[t] += x;
      __syncthreads();
    }
    if (t < NBLK) bsum[r * NBLK + t] = buf[t] - v;   // exclusive
    __syncthreads();
  }
}

// Phase 3: local exclusive scan + block base -> off. grid (NBLK, 4), 256 thr.
__global__ __launch_bounds__(256) void scan3_k(const int* __restrict__ cnt,
                                               const int* __restrict__ bsum,
                                               int* __restrict__ off) {
  __shared__ int lds[256];
  int b = blockIdx.x, r = blockIdx.y, t = threadIdx.x;
  int i0 = b * SCAN_B + t * 4;
  int c[4] = {0, 0, 0, 0};
#pragma unroll
  for (int j = 0; j < 4; ++j)
    if (i0 + j < N_NODES) c[j] = cnt[r * N_NODES + i0 + j];
  int s = c[0] + c[1] + c[2] + c[3];
  lds[t] = s;
  __syncthreads();
  for (int st = 1; st < 256; st <<= 1) {
    int x = (t >= st) ? lds[t - st] : 0;
    __syncthreads();
    lds[t] += x;
    __syncthreads();
  }
  int run = bsum[r * NBLK + b] + lds[t] - s;
  int* o = off + r * (N_NODES + 1);
#pragma unroll
  for (int j = 0; j < 4; ++j) {
    if (i0 + j < N_NODES) { o[i0 + j] = run; run += c[j]; }
  }
  if (b == 0 && t == 0) o[N_NODES] = NEDGE;
}

__global__ __launch_bounds__(256) void fill_csr_k(const int* __restrict__ sidx,
                                                  const int* __restrict__ didx,
                                                  const int* __restrict__ off,
                                                  int* __restrict__ cursor,
                                                  int* __restrict__ csr) {
  int e = blockIdx.x * 256 + threadIdx.x;
  int r = blockIdx.y;
  if (e >= NEDGE) return;
  int d = didx[r * NEDGE + e];
  int pos = off[r * (N_NODES + 1) + d] + atomicAdd(&cursor[r * N_NODES + d], 1);
  csr[r * NEDGE + pos] = sidx[r * NEDGE + e];
}

// f32 -> packed bf16 (2 per u32); each thread converts 8 floats.
__global__ __launch_bounds__(256) void cvt_bf16_k(const float* __restrict__ x,
                                                  unsigned* __restrict__ o) {
  int i = blockIdx.x * 256 + threadIdx.x;     // i < N_NODES*16
  if (i >= N_NODES * 16) return;
  f32x4 v0 = ((const f32x4*)x)[i * 2];
  f32x4 v1 = ((const f32x4*)x)[i * 2 + 1];
  unsigned r0 = (unsigned)(unsigned short)f2bf(v0[0]) |
                ((unsigned)(unsigned short)f2bf(v0[1]) << 16);
  unsigned r1 = (unsigned)(unsigned short)f2bf(v0[2]) |
                ((unsigned)(unsigned short)f2bf(v0[3]) << 16);
  unsigned r2 = (unsigned)(unsigned short)f2bf(v1[0]) |
                ((unsigned)(unsigned short)f2bf(v1[1]) << 16);
  unsigned r3 = (unsigned)(unsigned short)f2bf(v1[2]) |
                ((unsigned)(unsigned short)f2bf(v1[3]) << 16);
  typedef __attribute__((ext_vector_type(4))) unsigned u32x4;
  ((u32x4*)o)[i] = (u32x4){r0, r1, r2, r3};
}

// Pack combined weights into MFMA B-fragment-linear layout.
__global__ __launch_bounds__(256) void prep_w_k(const float* __restrict__ Ws1,
                                                const float* __restrict__ Wn1,
                                                const float* __restrict__ Ws2,
                                                const float* __restrict__ Wn2,
                                                short* __restrict__ WTp) {
  int tid = blockIdx.x * 256 + threadIdx.x;  // 0..98303
  int lane = tid & 63;
  int n0 = (tid >> 6) & 7;
  int idx3 = tid >> 9;
  int k0 = idx3 % 12;
  int lt = idx3 / 12;
  int l = lt >> 1, t = lt & 1;
  const float* Wself  = l ? Ws2 : Ws1;
  const float* Wneigh = l ? Wn2 : Wn1;
  int rA = t ? 0 : 1, rB = t ? 3 : 2;
  int n = n0 * 16 + (lane & 15);
  int kbase = k0 * 32 + (lane >> 4) * 8;
  short out[8];
#pragma unroll
  for (int j = 0; j < 8; ++j) {
    int k = kbase + j;
    int kk = k & 127, blk = k >> 7;
    float v;
    if (blk == 0)      v = Wself[rA * 16384 + kk * 128 + n] + Wself[rB * 16384 + kk * 128 + n];
    else if (blk == 1) v = Wneigh[rA * 16384 + kk * 128 + n];
    else               v = Wneigh[rB * 16384 + kk * 128 + n];
    out[j] = f2bf(v);
  }
  s16x4* dst = (s16x4*)&WTp[tid * 8];
  dst[0] = *(s16x4*)&out[0];
  dst[1] = *(s16x4*)&out[4];
}

__global__ __launch_bounds__(256) void prep_b_k(const float* __restrict__ b1,
                                                const float* __restrict__ b2,
                                                float* __restrict__ biasc) {
  int tid = blockIdx.x * 256 + threadIdx.x;
  if (tid >= 512) return;
  int l = tid >> 8, t = (tid >> 7) & 1, c = tid & 127;
  const float* b = l ? b2 : b1;
  int rA = t ? 0 : 1, rB = t ? 3 : 2;
  biasc[tid] = b[rA * 128 + c] + b[rB * 128 + c];
}

// One wave per (node, relation). 8-wide software-pipelined edge loop:
// 8 scalar csr loads -> 8 vector row loads in flight -> masked accumulate.
__global__ __launch_bounds__(256) void gather_mean_k(const unsigned* __restrict__ src,
    const int* __restrict__ csrA, const int* __restrict__ offA,
    const int* __restrict__ csrB, const int* __restrict__ offB,
    unsigned* __restrict__ meanA, unsigned* __restrict__ meanB) {
  int wv = __builtin_amdgcn_readfirstlane(threadIdx.x >> 6);
  int wid = blockIdx.x * 4 + wv;
  int lane = threadIdx.x & 63;
  int n = wid >> 1, rel = wid & 1;
  if (n >= N_NODES) return;
  const int* csr = rel ? csrB : csrA;
  const int* off = rel ? offB : offA;
  unsigned* mean = rel ? meanB : meanA;
  int p0 = off[n], p1 = off[n + 1];
  int deg = p1 - p0;
  float a0 = 0.f, a1 = 0.f;
  for (int p = p0; p < p1; p += 8) {
    int idx[8];
#pragma unroll
    for (int j = 0; j < 8; ++j) {
      int pc = p + j;
      idx[j] = csr[pc < p1 ? pc : p];
    }
    unsigned u[8];
#pragma unroll
    for (int j = 0; j < 8; ++j) u[j] = src[(size_t)idx[j] * 64 + lane];
#pragma unroll
    for (int j = 0; j < 8; ++j) {
      if (p + j < p1) {                       // wave-uniform branch
        union { unsigned q; float f; } xlo, xhi;
        xlo.q = u[j] << 16; xhi.q = u[j] & 0xffff0000u;
        a0 += xlo.f; a1 += xhi.f;
      }
    }
  }
  float inv = 1.0f / (float)(deg > 1 ? deg : 1);
  unsigned w = (unsigned)(unsigned short)f2bf(a0 * inv) |
               ((unsigned)(unsigned short)f2bf(a1 * inv) << 16);
  mean[(size_t)n * 64 + lane] = w;
}

// C[M=100000 x 128] = [self | meanA | meanB] (K=384, all bf16) @ W (in LDS)
template<int OUT_RELU_BF16>
__global__ __launch_bounds__(256) void gemm_k(const short* __restrict__ selfp,
    const short* __restrict__ meanA, const short* __restrict__ meanB,
    const short* __restrict__ WTp, const float* __restrict__ biasc,
    void* __restrict__ outp) {
  __shared__ short Wlds[6 * 8 * 512];   // 48KB
  int tid = threadIdx.x;
  int lane = tid & 63, wave = tid >> 6;
  int rowbase = blockIdx.x * 128 + wave * 32;
  int r0 = rowbase + (lane & 15), r1 = r0 + 16;
  int rc0 = r0 < N_NODES ? r0 : N_NODES - 1;
  int rc1 = r1 < N_NODES ? r1 : N_NODES - 1;
  int kg = lane >> 4;
  f32x4 acc[2][8] = {};
  for (int half = 0; half < 2; ++half) {
    __syncthreads();
    const f32x4* s = (const f32x4*)WTp + half * 3072;
    f32x4* dst = (f32x4*)Wlds;
#pragma unroll
    for (int i = 0; i < 12; ++i) dst[tid + i * 256] = s[tid + i * 256];
    __syncthreads();
    for (int k0h = 0; k0h < 6; ++k0h) {
      int k0 = half * 6 + k0h;
      int kin = (k0 & 3) * 32 + kg * 8;
      const short* mp = (k0 < 4) ? selfp : ((k0 < 8) ? meanA : meanB);
      bf16x8 a0 = *(const bf16x8*)(mp + (size_t)rc0 * 128 + kin);
      bf16x8 a1 = *(const bf16x8*)(mp + (size_t)rc1 * 128 + kin);
      const short* wb = &Wlds[k0h * 4096 + lane * 8];
#pragma unroll
      for (int n0 = 0; n0 < 8; ++n0) {
        bf16x8 b = *(const bf16x8*)(wb + n0 * 512);
        acc[0][n0] = __builtin_amdgcn_mfma_f32_16x16x32_bf16(a0, b, acc[0][n0], 0, 0, 0);
        acc[1][n0] = __builtin_amdgcn_mfma_f32_16x16x32_bf16(a1, b, acc[1][n0], 0, 0, 0);
      }
    }
  }
  int colb = lane & 15, rloc = kg * 4;
#pragma unroll
  for (int mt = 0; mt < 2; ++mt) {
    int rb = rowbase + mt * 16 + rloc;
#pragma unroll
    for (int n0 = 0; n0 < 8; ++n0) {
      int cc = n0 * 16 + colb;
      float bv = biasc[cc];
#pragma unroll
      for (int j = 0; j < 4; ++j) {
        int rr = rb + j;
        if (rr < N_NODES) {
          float v = acc[mt][n0][j] + bv;
          if (OUT_RELU_BF16) {
            ((short*)outp)[(size_t)rr * 128 + cc] = f2bf(v > 0.f ? v : 0.f);
          } else {
            ((float*)outp)[(size_t)rr * 128 + cc] = v;
          }
        }
      }
    }
  }
}

extern "C" void kernel_launch(void* const* d_in, const int* in_sizes, int n_in,
                              void* d_out, int out_size, void* d_ws, size_t ws_size,
                              hipStream_t stream) {
  (void)in_sizes; (void)n_in; (void)out_size; (void)ws_size;
  const float* xq  = (const float*)d_in[0];
  const float* xp  = (const float*)d_in[1];
  const int*   src = (const int*)d_in[2];
  const int*   dst = (const int*)d_in[3];
  const float* Ws1 = (const float*)d_in[4];
  const float* Wn1 = (const float*)d_in[5];
  const float* b1  = (const float*)d_in[6];
  const float* Ws2 = (const float*)d_in[7];
  const float* Wn2 = (const float*)d_in[8];
  const float* b2  = (const float*)d_in[9];

  char* w = (char*)d_ws;
  int*   cnt    = (int*)w;      w += (size_t)4 * N_NODES * 4;
  int*   cursor = (int*)w;      w += (size_t)4 * N_NODES * 4;
  int*   off    = (int*)w;      w += (size_t)4 * (N_NODES + 1) * 4;
  int*   csr    = (int*)w;      w += (size_t)4 * NEDGE * 4;
  short* meanA  = (short*)w;    w += (size_t)N_NODES * 128 * 2;
  short* meanB  = (short*)w;    w += (size_t)N_NODES * 128 * 2;
  short* h1q    = (short*)w;    w += (size_t)N_NODES * 128 * 2;
  short* h1p    = (short*)w;    w += (size_t)N_NODES * 128 * 2;
  short* xqb    = (short*)w;    w += (size_t)N_NODES * 128 * 2;
  short* xpb    = (short*)w;    w += (size_t)N_NODES * 128 * 2;
  short* WTp    = (short*)w;    w += (size_t)4 * 49152 * 2;
  float* biasc  = (float*)w;    w += 512 * 4;
  int*   bsum   = (int*)w;      w += 4 * 128 * 4;

  dim3 b256(256);
  const int egrid = (NEDGE + 255) / 256;          // 2344
  const int ggrid = (N_NODES + 127) / 128;        // 782
  const int wgrid = (2 * N_NODES + 3) / 4;        // 50000 (wave per node,rel)
  const int cgrid = (N_NODES * 16 + 255) / 256;   // 6250
  const int NP1 = N_NODES + 1;

  // --- CSR build (dst_idx fixed -> once per call, reused by both layers)
  hipMemsetAsync(cnt, 0, (size_t)8 * N_NODES * 4, stream);   // cnt + cursor
  count_deg_k<<<dim3(egrid, 4), b256, 0, stream>>>(dst, cnt);
  scan1_k<<<dim3(NBLK, 4), b256, 0, stream>>>(cnt, bsum);
  scan2_k<<<dim3(1), dim3(128), 0, stream>>>(bsum);
  scan3_k<<<dim3(NBLK, 4), b256, 0, stream>>>(cnt, bsum, off);
  fill_csr_k<<<dim3(egrid, 4), b256, 0, stream>>>(src, dst, off, cursor, csr);
  prep_w_k<<<dim3(384), b256, 0, stream>>>(Ws1, Wn1, Ws2, Wn2, WTp);
  prep_b_k<<<dim3(2), b256, 0, stream>>>(b1, b2, biasc);
  cvt_bf16_k<<<dim3(cgrid), b256, 0, stream>>>(xq, (unsigned*)xqb);
  cvt_bf16_k<<<dim3(cgrid), b256, 0, stream>>>(xp, (unsigned*)xpb);

  // ---- Layer 1, type 0 (Query): rels 1,2 ; src nodes = x_product (bf16)
  gather_mean_k<<<wgrid, b256, 0, stream>>>((const unsigned*)xpb,
      csr + 1 * NEDGE, off + 1 * NP1, csr + 2 * NEDGE, off + 2 * NP1,
      (unsigned*)meanA, (unsigned*)meanB);
  gemm_k<1><<<ggrid, b256, 0, stream>>>(xqb, meanA, meanB,
      WTp + 0 * 49152, biasc + 0, h1q);

  // ---- Layer 1, type 1 (Product): rels 0,3 ; src = x_query (bf16)
  gather_mean_k<<<wgrid, b256, 0, stream>>>((const unsigned*)xqb,
      csr + 0 * NEDGE, off + 0 * NP1, csr + 3 * NEDGE, off + 3 * NP1,
      (unsigned*)meanA, (unsigned*)meanB);
  gemm_k<1><<<ggrid, b256, 0, stream>>>(xpb, meanA, meanB,
      WTp + 1 * 49152, biasc + 128, h1p);

  // ---- Layer 2, type 0 (Query): rels 1,2 ; src = h1p (bf16)
  gather_mean_k<<<wgrid, b256, 0, stream>>>((const unsigned*)h1p,
      csr + 1 * NEDGE, off + 1 * NP1, csr + 2 * NEDGE, off + 2 * NP1,
      (unsigned*)meanA, (unsigned*)meanB);
  gemm_k<0><<<ggrid, b256, 0, stream>>>(h1q, meanA, meanB,
      WTp + 2 * 49152, biasc + 256, (float*)d_out);

  // ---- Layer 2, type 1 (Product): rels 0,3 ; src = h1q (bf16)
  gather_mean_k<<<wgrid, b256, 0, stream>>>((const unsigned*)h1q,
      csr + 0 * NEDGE, off + 0 * NP1, csr + 3 * NEDGE, off + 3 * NP1,
      (unsigned*)meanA, (unsigned*)meanB);
  gemm_k<0><<<ggrid, b256, 0, stream>>>(h1p, meanA, meanB,
      WTp + 3 * 49152, biasc + 384, (float*)d_out + (size_t)N_NODES * 128);
}

// Round 5
// 654.148 us; speedup vs baseline: 12.8355x; 1.1008x over previous
//
#include <hip/hip_runtime.h>
#include <hip/hip_bf16.h>

#define N_NODES 100000
#define NEDGE   600000
#define SCAN_B  1024
#define NBLK    98            // ceil(N_NODES / SCAN_B)
#define NCHUNK  293           // ceil(NEDGE / 2048)
#define XRANGE  12500         // N_NODES / 8 (per-XCD dst range)

typedef __attribute__((ext_vector_type(8))) short bf16x8;
typedef __attribute__((ext_vector_type(4))) short s16x4;
typedef __attribute__((ext_vector_type(4))) float f32x4;

__device__ __forceinline__ short f2bf(float f) {
  union { float f; unsigned u; } x; x.f = f;
  unsigned r = x.u + 0x7FFFu + ((x.u >> 16) & 1u);
  return (short)(r >> 16);
}

// count degrees AND record each edge's arrival rank within its dst bucket.
__global__ __launch_bounds__(256) void count_deg_k(const int* __restrict__ didx,
                                                   int* __restrict__ cnt,
                                                   int* __restrict__ rank) {
  int e = blockIdx.x * 256 + threadIdx.x;
  int r = blockIdx.y;
  if (e < NEDGE) {
    int d = didx[r * NEDGE + e];
    rank[(size_t)r * NEDGE + e] = atomicAdd(&cnt[r * N_NODES + d], 1);
  }
}

// Phase 1: per-block chunk sums. grid (NBLK, 4), 256 thr, 4 elems/thr.
__global__ __launch_bounds__(256) void scan1_k(const int* __restrict__ cnt,
                                               int* __restrict__ bsum) {
  __shared__ int lds[256];
  int b = blockIdx.x, r = blockIdx.y, t = threadIdx.x;
  int i0 = b * SCAN_B + t * 4;
  int s = 0;
#pragma unroll
  for (int j = 0; j < 4; ++j)
    if (i0 + j < N_NODES) s += cnt[r * N_NODES + i0 + j];
  lds[t] = s;
  __syncthreads();
  for (int st = 128; st > 0; st >>= 1) {
    if (t < st) lds[t] += lds[t + st];
    __syncthreads();
  }
  if (t == 0) bsum[r * NBLK + b] = lds[0];
}

// Phase 2: exclusive scan of the NBLK block sums per relation. 1 block, 128 thr.
__global__ __launch_bounds__(128) void scan2_k(int* __restrict__ bsum) {
  __shared__ int buf[128];
  int t = threadIdx.x;
  for (int r = 0; r < 4; ++r) {
    int v = (t < NBLK) ? bsum[r * NBLK + t] : 0;
    buf[t] = v;
    __syncthreads();
    for (int st = 1; st < 128; st <<= 1) {
      int x = (t >= st) ? buf[t - st] : 0;
      __syncthreads();
      buf[t] += x;
      __syncthreads();
    }
    if (t < NBLK) bsum[r * NBLK + t] = buf[t] - v;   // exclusive
    __syncthreads();
  }
}

// Phase 3: local exclusive scan + block base -> off. grid (NBLK, 4), 256 thr.
__global__ __launch_bounds__(256) void scan3_k(const int* __restrict__ cnt,
                                               const int* __restrict__ bsum,
                                               int* __restrict__ off) {
  __shared__ int lds[256];
  int b = blockIdx.x, r = blockIdx.y, t = threadIdx.x;
  int i0 = b * SCAN_B + t * 4;
  int c[4] = {0, 0, 0, 0};
#pragma unroll
  for (int j = 0; j < 4; ++j)
    if (i0 + j < N_NODES) c[j] = cnt[r * N_NODES + i0 + j];
  int s = c[0] + c[1] + c[2] + c[3];
  lds[t] = s;
  __syncthreads();
  for (int st = 1; st < 256; st <<= 1) {
    int x = (t >= st) ? lds[t - st] : 0;
    __syncthreads();
    lds[t] += x;
    __syncthreads();
  }
  int run = bsum[r * NBLK + b] + lds[t] - s;
  int* o = off + r * (N_NODES + 1);
#pragma unroll
  for (int j = 0; j < 4; ++j) {
    if (i0 + j < N_NODES) { o[i0 + j] = run; run += c[j]; }
  }
  if (b == 0 && t == 0) o[N_NODES] = NEDGE;
}

// Atomic-free, XCD-localized CSR fill. Block class g = bid&7 (round-robins to
// XCD g) owns dst range [g*XRANGE,(g+1)*XRANGE); each class re-scans the edge
// list (L2/L3-resident) and writes only its own csr range -> scattered writes
// stay within one XCD's L2 and lines fill up before write-back.
__global__ __launch_bounds__(256) void fill_csr_k(const int* __restrict__ sidx,
                                                  const int* __restrict__ didx,
                                                  const int* __restrict__ rank,
                                                  const int* __restrict__ off,
                                                  int* __restrict__ csr) {
  int b = blockIdx.x;
  int g = b & 7;                 // XCD class
  int c = b >> 3;                // edge chunk
  int r = blockIdx.y;
  int lo = g * XRANGE, hi = lo + XRANGE;
  const int* dd = didx + (size_t)r * NEDGE;
  const int* ss = sidx + (size_t)r * NEDGE;
  const int* rk = rank + (size_t)r * NEDGE;
  const int* of = off + r * (N_NODES + 1);
  int* cs = csr + (size_t)r * NEDGE;
  int base = c * 2048 + threadIdx.x;
#pragma unroll
  for (int j = 0; j < 8; ++j) {
    int e = base + j * 256;
    if (e < NEDGE) {
      int d = dd[e];
      if (d >= lo && d < hi) cs[of[d] + rk[e]] = ss[e];
    }
  }
}

// f32 -> packed bf16 (2 per u32); each thread converts 8 floats.
__global__ __launch_bounds__(256) void cvt_bf16_k(const float* __restrict__ x,
                                                  unsigned* __restrict__ o) {
  int i = blockIdx.x * 256 + threadIdx.x;     // i < N_NODES*16
  if (i >= N_NODES * 16) return;
  f32x4 v0 = ((const f32x4*)x)[i * 2];
  f32x4 v1 = ((const f32x4*)x)[i * 2 + 1];
  unsigned r0 = (unsigned)(unsigned short)f2bf(v0[0]) |
                ((unsigned)(unsigned short)f2bf(v0[1]) << 16);
  unsigned r1 = (unsigned)(unsigned short)f2bf(v0[2]) |
                ((unsigned)(unsigned short)f2bf(v0[3]) << 16);
  unsigned r2 = (unsigned)(unsigned short)f2bf(v1[0]) |
                ((unsigned)(unsigned short)f2bf(v1[1]) << 16);
  unsigned r3 = (unsigned)(unsigned short)f2bf(v1[2]) |
                ((unsigned)(unsigned short)f2bf(v1[3]) << 16);
  typedef __attribute__((ext_vector_type(4))) unsigned u32x4;
  ((u32x4*)o)[i] = (u32x4){r0, r1, r2, r3};
}

// Pack combined weights into MFMA B-fragment-linear layout.
__global__ __launch_bounds__(256) void prep_w_k(const float* __restrict__ Ws1,
                                                const float* __restrict__ Wn1,
                                                const float* __restrict__ Ws2,
                                                const float* __restrict__ Wn2,
                                                short* __restrict__ WTp) {
  int tid = blockIdx.x * 256 + threadIdx.x;  // 0..98303
  int lane = tid & 63;
  int n0 = (tid >> 6) & 7;
  int idx3 = tid >> 9;
  int k0 = idx3 % 12;
  int lt = idx3 / 12;
  int l = lt >> 1, t = lt & 1;
  const float* Wself  = l ? Ws2 : Ws1;
  const float* Wneigh = l ? Wn2 : Wn1;
  int rA = t ? 0 : 1, rB = t ? 3 : 2;
  int n = n0 * 16 + (lane & 15);
  int kbase = k0 * 32 + (lane >> 4) * 8;
  short out[8];
#pragma unroll
  for (int j = 0; j < 8; ++j) {
    int k = kbase + j;
    int kk = k & 127, blk = k >> 7;
    float v;
    if (blk == 0)      v = Wself[rA * 16384 + kk * 128 + n] + Wself[rB * 16384 + kk * 128 + n];
    else if (blk == 1) v = Wneigh[rA * 16384 + kk * 128 + n];
    else               v = Wneigh[rB * 16384 + kk * 128 + n];
    out[j] = f2bf(v);
  }
  s16x4* dst = (s16x4*)&WTp[tid * 8];
  dst[0] = *(s16x4*)&out[0];
  dst[1] = *(s16x4*)&out[4];
}

__global__ __launch_bounds__(256) void prep_b_k(const float* __restrict__ b1,
                                                const float* __restrict__ b2,
                                                float* __restrict__ biasc) {
  int tid = blockIdx.x * 256 + threadIdx.x;
  if (tid >= 512) return;
  int l = tid >> 8, t = (tid >> 7) & 1, c = tid & 127;
  const float* b = l ? b2 : b1;
  int rA = t ? 0 : 1, rB = t ? 3 : 2;
  biasc[tid] = b[rA * 128 + c] + b[rB * 128 + c];
}

// One wave per (node, relation). 8-wide software-pipelined edge loop.
__global__ __launch_bounds__(256) void gather_mean_k(const unsigned* __restrict__ src,
    const int* __restrict__ csrA, const int* __restrict__ offA,
    const int* __restrict__ csrB, const int* __restrict__ offB,
    unsigned* __restrict__ meanA, unsigned* __restrict__ meanB) {
  int wv = __builtin_amdgcn_readfirstlane(threadIdx.x >> 6);
  int wid = blockIdx.x * 4 + wv;
  int lane = threadIdx.x & 63;
  int n = wid >> 1, rel = wid & 1;
  if (n >= N_NODES) return;
  const int* csr = rel ? csrB : csrA;
  const int* off = rel ? offB : offA;
  unsigned* mean = rel ? meanB : meanA;
  int p0 = off[n], p1 = off[n + 1];
  int deg = p1 - p0;
  float a0 = 0.f, a1 = 0.f;
  for (int p = p0; p < p1; p += 8) {
    int idx[8];
#pragma unroll
    for (int j = 0; j < 8; ++j) {
      int pc = p + j;
      idx[j] = csr[pc < p1 ? pc : p];
    }
    unsigned u[8];
#pragma unroll
    for (int j = 0; j < 8; ++j) u[j] = src[(size_t)idx[j] * 64 + lane];
#pragma unroll
    for (int j = 0; j < 8; ++j) {
      if (p + j < p1) {                       // wave-uniform branch
        union { unsigned q; float f; } xlo, xhi;
        xlo.q = u[j] << 16; xhi.q = u[j] & 0xffff0000u;
        a0 += xlo.f; a1 += xhi.f;
      }
    }
  }
  float inv = 1.0f / (float)(deg > 1 ? deg : 1);
  unsigned w = (unsigned)(unsigned short)f2bf(a0 * inv) |
               ((unsigned)(unsigned short)f2bf(a1 * inv) << 16);
  mean[(size_t)n * 64 + lane] = w;
}

// C[M=100000 x 128] = [self | meanA | meanB] (K=384, all bf16) @ W (in LDS)
template<int OUT_RELU_BF16>
__global__ __launch_bounds__(256) void gemm_k(const short* __restrict__ selfp,
    const short* __restrict__ meanA, const short* __restrict__ meanB,
    const short* __restrict__ WTp, const float* __restrict__ biasc,
    void* __restrict__ outp) {
  __shared__ short Wlds[6 * 8 * 512];   // 48KB
  int tid = threadIdx.x;
  int lane = tid & 63, wave = tid >> 6;
  int rowbase = blockIdx.x * 128 + wave * 32;
  int r0 = rowbase + (lane & 15), r1 = r0 + 16;
  int rc0 = r0 < N_NODES ? r0 : N_NODES - 1;
  int rc1 = r1 < N_NODES ? r1 : N_NODES - 1;
  int kg = lane >> 4;
  f32x4 acc[2][8] = {};
  for (int half = 0; half < 2; ++half) {
    __syncthreads();
    const f32x4* s = (const f32x4*)WTp + half * 3072;
    f32x4* dst = (f32x4*)Wlds;
#pragma unroll
    for (int i = 0; i < 12; ++i) dst[tid + i * 256] = s[tid + i * 256];
    __syncthreads();
    for (int k0h = 0; k0h < 6; ++k0h) {
      int k0 = half * 6 + k0h;
      int kin = (k0 & 3) * 32 + kg * 8;
      const short* mp = (k0 < 4) ? selfp : ((k0 < 8) ? meanA : meanB);
      bf16x8 a0 = *(const bf16x8*)(mp + (size_t)rc0 * 128 + kin);
      bf16x8 a1 = *(const bf16x8*)(mp + (size_t)rc1 * 128 + kin);
      const short* wb = &Wlds[k0h * 4096 + lane * 8];
#pragma unroll
      for (int n0 = 0; n0 < 8; ++n0) {
        bf16x8 b = *(const bf16x8*)(wb + n0 * 512);
        acc[0][n0] = __builtin_amdgcn_mfma_f32_16x16x32_bf16(a0, b, acc[0][n0], 0, 0, 0);
        acc[1][n0] = __builtin_amdgcn_mfma_f32_16x16x32_bf16(a1, b, acc[1][n0], 0, 0, 0);
      }
    }
  }
  int colb = lane & 15, rloc = kg * 4;
#pragma unroll
  for (int mt = 0; mt < 2; ++mt) {
    int rb = rowbase + mt * 16 + rloc;
#pragma unroll
    for (int n0 = 0; n0 < 8; ++n0) {
      int cc = n0 * 16 + colb;
      float bv = biasc[cc];
#pragma unroll
      for (int j = 0; j < 4; ++j) {
        int rr = rb + j;
        if (rr < N_NODES) {
          float v = acc[mt][n0][j] + bv;
          if (OUT_RELU_BF16) {
            ((short*)outp)[(size_t)rr * 128 + cc] = f2bf(v > 0.f ? v : 0.f);
          } else {
            ((float*)outp)[(size_t)rr * 128 + cc] = v;
          }
        }
      }
    }
  }
}

extern "C" void kernel_launch(void* const* d_in, const int* in_sizes, int n_in,
                              void* d_out, int out_size, void* d_ws, size_t ws_size,
                              hipStream_t stream) {
  (void)in_sizes; (void)n_in; (void)out_size; (void)ws_size;
  const float* xq  = (const float*)d_in[0];
  const float* xp  = (const float*)d_in[1];
  const int*   src = (const int*)d_in[2];
  const int*   dst = (const int*)d_in[3];
  const float* Ws1 = (const float*)d_in[4];
  const float* Wn1 = (const float*)d_in[5];
  const float* b1  = (const float*)d_in[6];
  const float* Ws2 = (const float*)d_in[7];
  const float* Wn2 = (const float*)d_in[8];
  const float* b2  = (const float*)d_in[9];

  char* w = (char*)d_ws;
  int*   cnt    = (int*)w;      w += (size_t)4 * N_NODES * 4;
  int*   off    = (int*)w;      w += (size_t)4 * (N_NODES + 1) * 4;
  int*   csr    = (int*)w;      w += (size_t)4 * NEDGE * 4;
  short* meanA  = (short*)w;    w += (size_t)N_NODES * 128 * 2;
  short* meanB  = (short*)w;    w += (size_t)N_NODES * 128 * 2;
  short* h1q    = (short*)w;    w += (size_t)N_NODES * 128 * 2;
  short* h1p    = (short*)w;    w += (size_t)N_NODES * 128 * 2;
  short* xqb    = (short*)w;    w += (size_t)N_NODES * 128 * 2;
  short* xpb    = (short*)w;    w += (size_t)N_NODES * 128 * 2;
  short* WTp    = (short*)w;    w += (size_t)4 * 49152 * 2;
  float* biasc  = (float*)w;    w += 512 * 4;
  int*   bsum   = (int*)w;      w += 4 * 128 * 4;
  // rank is only live during CSR build, before meanA/meanB are first written:
  int*   rank   = (int*)meanA;  // 9.6 MB <= 25.6 MB (meanA region)

  dim3 b256(256);
  const int egrid = (NEDGE + 255) / 256;          // 2344
  const int ggrid = (N_NODES + 127) / 128;        // 782
  const int wgrid = (2 * N_NODES + 3) / 4;        // 50000 (wave per node,rel)
  const int cgrid = (N_NODES * 16 + 255) / 256;   // 6250
  const int NP1 = N_NODES + 1;

  // --- CSR build (dst_idx fixed -> once per call, reused by both layers)
  hipMemsetAsync(cnt, 0, (size_t)4 * N_NODES * 4, stream);
  count_deg_k<<<dim3(egrid, 4), b256, 0, stream>>>(dst, cnt, rank);
  scan1_k<<<dim3(NBLK, 4), b256, 0, stream>>>(cnt, bsum);
  scan2_k<<<dim3(1), dim3(128), 0, stream>>>(bsum);
  scan3_k<<<dim3(NBLK, 4), b256, 0, stream>>>(cnt, bsum, off);
  fill_csr_k<<<dim3(NCHUNK * 8, 4), b256, 0, stream>>>(src, dst, rank, off, csr);
  prep_w_k<<<dim3(384), b256, 0, stream>>>(Ws1, Wn1, Ws2, Wn2, WTp);
  prep_b_k<<<dim3(2), b256, 0, stream>>>(b1, b2, biasc);
  cvt_bf16_k<<<dim3(cgrid), b256, 0, stream>>>(xq, (unsigned*)xqb);
  cvt_bf16_k<<<dim3(cgrid), b256, 0, stream>>>(xp, (unsigned*)xpb);

  // ---- Layer 1, type 0 (Query): rels 1,2 ; src nodes = x_product (bf16)
  gather_mean_k<<<wgrid, b256, 0, stream>>>((const unsigned*)xpb,
      csr + 1 * NEDGE, off + 1 * NP1, csr + 2 * NEDGE, off + 2 * NP1,
      (unsigned*)meanA, (unsigned*)meanB);
  gemm_k<1><<<ggrid, b256, 0, stream>>>(xqb, meanA, meanB,
      WTp + 0 * 49152, biasc + 0, h1q);

  // ---- Layer 1, type 1 (Product): rels 0,3 ; src = x_query (bf16)
  gather_mean_k<<<wgrid, b256, 0, stream>>>((const unsigned*)xqb,
      csr + 0 * NEDGE, off + 0 * NP1, csr + 3 * NEDGE, off + 3 * NP1,
      (unsigned*)meanA, (unsigned*)meanB);
  gemm_k<1><<<ggrid, b256, 0, stream>>>(xpb, meanA, meanB,
      WTp + 1 * 49152, biasc + 128, h1p);

  // ---- Layer 2, type 0 (Query): rels 1,2 ; src = h1p (bf16)
  gather_mean_k<<<wgrid, b256, 0, stream>>>((const unsigned*)h1p,
      csr + 1 * NEDGE, off + 1 * NP1, csr + 2 * NEDGE, off + 2 * NP1,
      (unsigned*)meanA, (unsigned*)meanB);
  gemm_k<0><<<ggrid, b256, 0, stream>>>(h1q, meanA, meanB,
      WTp + 2 * 49152, biasc + 256, (float*)d_out);

  // ---- Layer 2, type 1 (Product): rels 0,3 ; src = h1q (bf16)
  gather_mean_k<<<wgrid, b256, 0, stream>>>((const unsigned*)h1q,
      csr + 0 * NEDGE, off + 0 * NP1, csr + 3 * NEDGE, off + 3 * NP1,
      (unsigned*)meanA, (unsigned*)meanB);
  gemm_k<0><<<ggrid, b256, 0, stream>>>(h1p, meanA, meanB,
      WTp + 3 * 49152, biasc + 384, (float*)d_out + (size_t)N_NODES * 128);
}